// Round 10
// baseline (54.753 us; speedup 1.0000x reference)
//
#include <hip/hip_runtime.h>

// Problem dims (fixed by reference setup_inputs):
#define BATCH 1024
#define NSEQ  512
#define NF    64
#define HIST_BINS 1024     // ids in [0,1000)

#define HOT 16             // table rows in LDS (counts ~Poisson(0.5), max ~7; P(>=16)~1e-18)

// ---------------------------------------------------------------------------
// SINGLE kernel. Block 2*row+which owns batch-row `row` of tensor `which`
// (0 = src-encoding, 1 = dst-encoding): 128 KB contiguous float4 stores.
//
// Prologue (per block, overlapped across 8 blocks/CU):
//   - issue id loads into registers FIRST (latency hides under VALU/LDS work)
//   - zero histograms
//   - compute HOT table rows in-block: tbl[r][g] = b2[g] + sum_f relu(r*W1[f]
//     + b1[f]) * W2[f][g]  (256 MACs/thread; W2 reads lane-coalesced, L2-hot)
//     -> removes the serialized build_table kernel AND 16 MB of table copies.
//   - histogram both id rows (LDS atomics)
//   - per-position clamped LDS byte offsets; count>=HOT -> overflow list
//
// Hot loop (branch-free; vmem pipe carries ONLY stores; plain float4 --
// nt stores confirmed -32% in R8): 2x ds_read_b128 + 4 adds + store_dwordx4.
// Overflow positions fixed up AFTER the loop by direct computation.
// ---------------------------------------------------------------------------
__global__ __launch_bounds__(256) void fused_kernel(
        const int* __restrict__ src_ids,
        const int* __restrict__ dst_ids,
        const float* __restrict__ W1,
        const float* __restrict__ b1,
        const float* __restrict__ W2,
        const float* __restrict__ b2,
        float* __restrict__ out) {
    __shared__ int            hist_s[HIST_BINS];
    __shared__ int            hist_d[HIST_BINS];
    __shared__ float          s_tbl[HOT * NF];     // 4 KB
    __shared__ ushort2        s_off[NSEQ];         // clamped byte offsets (own,cross)
    __shared__ unsigned short s_ovf[NSEQ];
    __shared__ int            s_novf;

    const int t     = threadIdx.x;
    const int which = blockIdx.x & 1;
    const int row   = blockIdx.x >> 1;

    // ---- issue id loads first: 2 src + 2 dst ints per thread ----
    const size_t rb = (size_t)row * NSEQ;
    const int si0 = src_ids[rb + t];
    const int si1 = src_ids[rb + t + 256];
    const int di0 = dst_ids[rb + t];
    const int di1 = dst_ids[rb + t + 256];

    // zero histograms + ovf counter
#pragma unroll
    for (int i = t; i < HIST_BINS; i += 256) { hist_s[i] = 0; hist_d[i] = 0; }
    if (t == 0) s_novf = 0;

    // ---- compute HOT table rows into LDS (4 entries per thread) ----
    // entry idx = t + k*256 -> (r = idx>>6, g = idx&63); lanes g=0..63 read
    // W2[f*64+g] consecutively -> coalesced; W1/b1/b2/W2 are L2-resident.
#pragma unroll
    for (int k = 0; k < (HOT * NF) / 256; ++k) {   // 4 iterations
        const int idx = t + k * 256;
        const int r = idx >> 6, g = idx & 63;
        const float cf = (float)r;
        float acc = b2[g];
#pragma unroll 8
        for (int f = 0; f < NF; ++f) {
            float h = fmaxf(cf * W1[f] + b1[f], 0.0f);
            acc += h * W2[f * NF + g];
        }
        s_tbl[r * NF + g] = acc;
    }
    __syncthreads();

    // ---- histogram both rows (guard padded id = -1) ----
    if (si0 >= 0) atomicAdd(&hist_s[si0], 1);
    if (si1 >= 0) atomicAdd(&hist_s[si1], 1);
    if (di0 >= 0) atomicAdd(&hist_d[di0], 1);
    if (di1 >= 0) atomicAdd(&hist_d[di1], 1);
    __syncthreads();

    // ---- per-position clamped byte offsets for THIS tensor ----
#pragma unroll
    for (int u = 0; u < 2; ++u) {
        const int i  = t + u * 256;
        const int id = (which == 0) ? (u ? si1 : si0) : (u ? di1 : di0);
        int own = 0, cross = 0;
        if (id >= 0) {
            own   = (which == 0) ? hist_s[id] : hist_d[id];
            cross = (which == 0) ? hist_d[id] : hist_s[id];
        }
        if (own >= HOT || cross >= HOT) {
            int k = atomicAdd(&s_novf, 1);
            s_ovf[k] = (unsigned short)i;
        }
        ushort2 off;
        off.x = (unsigned short)(min(own,   HOT - 1) * (NF * 4));
        off.y = (unsigned short)(min(cross, HOT - 1) * (NF * 4));
        s_off[i] = off;
    }
    __syncthreads();

    // ---- hot store stream: vmem pipe = stores only ----
    float4* __restrict__ o = (float4*)(out + ((size_t)which * BATCH + row) * NSEQ * NF);
    const char* __restrict__ tb = (const char*)s_tbl;
    const int NV = NSEQ * NF / 4;   // 8192 float4
#pragma unroll 4
    for (int e = t; e < NV; e += 256) {
        const int n  = e >> 4;           // position (16 float4 per position)
        const int fb = (e & 15) << 4;    // byte offset within row
        const ushort2 c = s_off[n];
        const float4 a0 = *(const float4*)(tb + (int)c.x + fb);
        const float4 a1 = *(const float4*)(tb + (int)c.y + fb);
        o[e] = make_float4(a0.x + a1.x, a0.y + a1.y, a0.z + a1.z, a0.w + a1.w);
    }

    // ---- rare fixup for counts >= HOT: compute directly (no global table) ----
    __syncthreads();
    const int novf = s_novf;
    if (novf > 0) {
        const int* __restrict__ own_ids = (which == 0) ? src_ids : dst_ids;
        for (int k = t >> 4; k < novf; k += 16) {
            const int i  = s_ovf[k];
            const int f4 = t & 15;
            const int g0 = f4 * 4;
            const int id = own_ids[rb + i];
            int own = 0, cross = 0;
            if (id >= 0) {
                own   = (which == 0) ? hist_s[id] : hist_d[id];
                cross = (which == 0) ? hist_d[id] : hist_s[id];
            }
            float a0 = 2.0f * b2[g0 + 0], a1 = 2.0f * b2[g0 + 1];
            float a2 = 2.0f * b2[g0 + 2], a3 = 2.0f * b2[g0 + 3];
            for (int f = 0; f < NF; ++f) {
                float w = W1[f], b = b1[f];
                float hs = fmaxf((float)own * w + b, 0.0f)
                         + fmaxf((float)cross * w + b, 0.0f);
                const float* w2 = &W2[f * NF + g0];
                a0 += hs * w2[0]; a1 += hs * w2[1];
                a2 += hs * w2[2]; a3 += hs * w2[3];
            }
            o[i * 16 + f4] = make_float4(a0, a1, a2, a3);
        }
    }
}

extern "C" void kernel_launch(void* const* d_in, const int* in_sizes, int n_in,
                              void* d_out, int out_size, void* d_ws, size_t ws_size,
                              hipStream_t stream) {
    const int*   src_ids = (const int*)d_in[0];
    const int*   dst_ids = (const int*)d_in[1];
    const float* W1 = (const float*)d_in[2];   // [1, F]
    const float* b1 = (const float*)d_in[3];   // [F]
    const float* W2 = (const float*)d_in[4];   // [F, F]
    const float* b2 = (const float*)d_in[5];   // [F]

    float* out = (float*)d_out;   // [2, B, N, F] flat (src encoding, then dst)

    fused_kernel<<<2 * BATCH, 256, 0, stream>>>(src_ids, dst_ids,
                                                W1, b1, W2, b2, out);
}

// Round 11
// 51.590 us; speedup vs baseline: 1.0613x; 1.0613x over previous
//
#include <hip/hip_runtime.h>

// Problem dims (fixed by reference setup_inputs):
#define BATCH 1024
#define NSEQ  512
#define NF    64
#define TBL_N (NSEQ + 1)   // counts range 0..512
#define HIST_BINS 1024     // ids in [0,1000)

#define HOT 32             // table rows staged in LDS (counts ~Poisson(0.5), max~7)
#define TBL_BLOCKS ((TBL_N + 3) / 4)

// Dummy LDS pad to force occupancy DOWN to 2 blocks/CU (total LDS ~64 KB).
// Hypothesis under test: 32 interleaved store streams/CU degrade HBM
// row-buffer locality vs the fill kernel's ~3 waves/CU at 7.0 TB/s.
#define PAD_FLOATS 11520   // 45 KB

// ---------------------------------------------------------------------------
// Kernel 1: full lookup table into workspace.
// tbl[c][g] = b2[g] + sum_f relu(c*W1[f]+b1[f]) * W2[f][g]
// ---------------------------------------------------------------------------
__global__ __launch_bounds__(256) void build_table_kernel(
        const float* __restrict__ W1,
        const float* __restrict__ b1,
        const float* __restrict__ W2,
        const float* __restrict__ b2,
        float* __restrict__ tbl) {
    const int c = blockIdx.x * 4 + (threadIdx.x >> 6);
    const int g = threadIdx.x & 63;
    if (c >= TBL_N) return;
    const float cf = (float)c;
    float acc = b2[g];
#pragma unroll 8
    for (int f = 0; f < NF; ++f) {
        float h = fmaxf(cf * W1[f] + b1[f], 0.0f);
        acc += h * W2[f * NF + g];
    }
    tbl[c * NF + g] = acc;
}

// ---------------------------------------------------------------------------
// Kernel 2: IDENTICAL to R7's writer except the LDS pad (occupancy probe).
// Block 2*row+which owns batch-row `row` of tensor `which`.
// Hot loop: ds_read_b32 + 2x ds_read_b128 + 4 adds + global_store_dwordx4.
// ---------------------------------------------------------------------------
__global__ __launch_bounds__(256) void expand_kernel(
        const int* __restrict__ src_ids,
        const int* __restrict__ dst_ids,
        const float* __restrict__ g_tbl,
        float* __restrict__ out) {
    __shared__ int            hist_s[HIST_BINS];
    __shared__ int            hist_d[HIST_BINS];
    __shared__ float          s_tbl[HOT * NF];      // 8 KB, stride 64
    __shared__ ushort2        s_off[NSEQ];          // clamped byte offsets (c1,c2)
    __shared__ unsigned short s_ovf[NSEQ];          // overflow positions
    __shared__ int            s_novf;
    __shared__ float          s_pad[PAD_FLOATS];    // occupancy limiter (never touched)

    const int t     = threadIdx.x;
    const int which = blockIdx.x & 1;    // 0 = src-encoding, 1 = dst-encoding
    const int row   = blockIdx.x >> 1;

    // opaque guard: compiler cannot prove gridDim, so s_pad stays allocated
    if (blockIdx.x == 0xFFFFFFFFu) {
        s_pad[t] = (float)t;
        __syncthreads();
        out[t] = s_pad[(t + 1) & (PAD_FLOATS - 1)];
    }

    const int* __restrict__ own_ids = (which == 0) ? src_ids : dst_ids;

    // zero histograms + ovf counter
#pragma unroll
    for (int i = t; i < HIST_BINS; i += 256) { hist_s[i] = 0; hist_d[i] = 0; }
    if (t == 0) s_novf = 0;

    // copy hot table rows global -> LDS (2 float4 per thread)
    {
        const float4* __restrict__ g4 = (const float4*)g_tbl;
        float4* __restrict__ l4 = (float4*)s_tbl;
#pragma unroll
        for (int i = t; i < HOT * NF / 4; i += 256) l4[i] = g4[i];
    }
    __syncthreads();

    // histogram both rows (guard padded id = -1)
#pragma unroll
    for (int i = t; i < NSEQ; i += 256) {
        int si = src_ids[(size_t)row * NSEQ + i];
        int di = dst_ids[(size_t)row * NSEQ + i];
        if (si >= 0) atomicAdd(&hist_s[si], 1);
        if (di >= 0) atomicAdd(&hist_d[di], 1);
    }
    __syncthreads();

    // per-position clamped byte offsets for THIS tensor; overflow -> list
#pragma unroll
    for (int i = t; i < NSEQ; i += 256) {
        int id = own_ids[(size_t)row * NSEQ + i];
        int own = 0, cross = 0;
        if (id >= 0) {
            own   = (which == 0) ? hist_s[id] : hist_d[id];
            cross = (which == 0) ? hist_d[id] : hist_s[id];
        }
        if (own >= HOT || cross >= HOT) {
            int k = atomicAdd(&s_novf, 1);
            s_ovf[k] = (unsigned short)i;
        }
        ushort2 off;
        off.x = (unsigned short)(min(own,   HOT - 1) * (NF * 4));
        off.y = (unsigned short)(min(cross, HOT - 1) * (NF * 4));
        s_off[i] = off;
    }
    __syncthreads();

    // ---- hot store stream: vmem pipe carries ONLY stores ----
    float4* __restrict__ o = (float4*)(out + ((size_t)which * BATCH + row) * NSEQ * NF);
    const char* __restrict__ tb = (const char*)s_tbl;
    const int NV = NSEQ * NF / 4;   // 8192 float4
#pragma unroll 4
    for (int e = t; e < NV; e += 256) {
        const int n  = e >> 4;           // position (16 float4 per position)
        const int fb = (e & 15) << 4;    // byte offset within row
        const ushort2 c = s_off[n];
        const float4 a0 = *(const float4*)(tb + (int)c.x + fb);
        const float4 a1 = *(const float4*)(tb + (int)c.y + fb);
        o[e] = make_float4(a0.x + a1.x, a0.y + a1.y, a0.z + a1.z, a0.w + a1.w);
    }

    // ---- rare fixup for counts >= HOT (reads global table) ----
    __syncthreads();
    const int novf = s_novf;
    if (novf > 0) {
        const float4* __restrict__ g4 = (const float4*)g_tbl;
        for (int k = t >> 4; k < novf; k += 16) {
            const int i  = s_ovf[k];
            const int f4 = t & 15;
            const int id = own_ids[(size_t)row * NSEQ + i];
            int own = 0, cross = 0;
            if (id >= 0) {
                own   = (which == 0) ? hist_s[id] : hist_d[id];
                cross = (which == 0) ? hist_d[id] : hist_s[id];
            }
            float4 a0 = g4[own * (NF / 4) + f4];
            float4 a1 = g4[cross * (NF / 4) + f4];
            o[i * 16 + f4] = make_float4(a0.x + a1.x, a0.y + a1.y,
                                         a0.z + a1.z, a0.w + a1.w);
        }
    }
}

extern "C" void kernel_launch(void* const* d_in, const int* in_sizes, int n_in,
                              void* d_out, int out_size, void* d_ws, size_t ws_size,
                              hipStream_t stream) {
    const int*   src_ids = (const int*)d_in[0];
    const int*   dst_ids = (const int*)d_in[1];
    const float* W1 = (const float*)d_in[2];   // [1, F]
    const float* b1 = (const float*)d_in[3];   // [F]
    const float* W2 = (const float*)d_in[4];   // [F, F]
    const float* b2 = (const float*)d_in[5];   // [F]

    float* out = (float*)d_out;   // [2, B, N, F] flat (src encoding, then dst)
    float* tbl = (float*)d_ws;    // TBL_N * NF f32 = 131,328 B

    build_table_kernel<<<TBL_BLOCKS, 256, 0, stream>>>(W1, b1, W2, b2, tbl);
    expand_kernel<<<2 * BATCH, 256, 0, stream>>>(src_ids, dst_ids, tbl, out);
}

// Round 12
// 50.992 us; speedup vs baseline: 1.0737x; 1.0117x over previous
//
#include <hip/hip_runtime.h>

// Problem dims (fixed by reference setup_inputs):
#define BATCH 1024
#define NSEQ  512
#define NF    64
#define TBL_N (NSEQ + 1)   // counts range 0..512
#define HIST_BINS 1024     // ids in [0,1000)

#define HOT 32             // table rows staged in LDS (counts ~Poisson(0.5), max~7)
#define TBL_BLOCKS ((TBL_N + 3) / 4)   // 129 blocks x (4 c-values * 64 threads)

// ============================================================================
// FINAL (champion, R7): 51.0 us. Roofline accounting:
//   268 MB mandatory f32 stores + ~24 MB reads at ~6.3 TB/s achievable
//   mixed-traffic HBM BW = ~46 us, + table kernel/launch ~4 us = ~51 us.
// Verified null/harmful: gather-source variants (global/LDS/precomputed),
// nt stores (-32%), prologue pipelining, occupancy 2..8 blocks/CU,
// in-block table recompute. See session journal R3-R11.
// ============================================================================

// ---------------------------------------------------------------------------
// Kernel 1: full lookup table into workspace.
// tbl[c][g] = b2[g] + sum_f relu(c*W1[f]+b1[f]) * W2[f][g]
// ---------------------------------------------------------------------------
__global__ __launch_bounds__(256) void build_table_kernel(
        const float* __restrict__ W1,
        const float* __restrict__ b1,
        const float* __restrict__ W2,
        const float* __restrict__ b2,
        float* __restrict__ tbl) {
    const int c = blockIdx.x * 4 + (threadIdx.x >> 6);
    const int g = threadIdx.x & 63;
    if (c >= TBL_N) return;
    const float cf = (float)c;
    float acc = b2[g];
#pragma unroll 8
    for (int f = 0; f < NF; ++f) {
        float h = fmaxf(cf * W1[f] + b1[f], 0.0f);
        acc += h * W2[f * NF + g];
    }
    tbl[c * NF + g] = acc;
}

// ---------------------------------------------------------------------------
// Kernel 2: writer. Block 2*row+which owns batch-row `row` of tensor `which`
// (0 = src-encoding, 1 = dst-encoding): 128 KB contiguous float4 stores.
// Prologue: histogram both id rows (LDS atomics), copy hot table rows
// (32 x 64 f32 = 8 KB) global->LDS, precompute per-position CLAMPED LDS byte
// offsets. Hot loop is branch-free and store-only on the vmem pipe:
//   ds_read_b32 + 2x ds_read_b128 + 4 adds + global_store_dwordx4.
// Positions with count >= HOT (never for this input) -> overflow list,
// fixed up after the main loop from the global table.
// ---------------------------------------------------------------------------
__global__ __launch_bounds__(256) void expand_kernel(
        const int* __restrict__ src_ids,
        const int* __restrict__ dst_ids,
        const float* __restrict__ g_tbl,
        float* __restrict__ out) {
    __shared__ int            hist_s[HIST_BINS];
    __shared__ int            hist_d[HIST_BINS];
    __shared__ float          s_tbl[HOT * NF];      // 8 KB, stride 64
    __shared__ ushort2        s_off[NSEQ];          // clamped byte offsets (c1,c2)
    __shared__ unsigned short s_ovf[NSEQ];          // overflow positions
    __shared__ int            s_novf;

    const int t     = threadIdx.x;
    const int which = blockIdx.x & 1;    // 0 = src-encoding, 1 = dst-encoding
    const int row   = blockIdx.x >> 1;

    const int* __restrict__ own_ids = (which == 0) ? src_ids : dst_ids;

    // zero histograms + ovf counter
#pragma unroll
    for (int i = t; i < HIST_BINS; i += 256) { hist_s[i] = 0; hist_d[i] = 0; }
    if (t == 0) s_novf = 0;

    // copy hot table rows global -> LDS (2 float4 per thread)
    {
        const float4* __restrict__ g4 = (const float4*)g_tbl;
        float4* __restrict__ l4 = (float4*)s_tbl;
#pragma unroll
        for (int i = t; i < HOT * NF / 4; i += 256) l4[i] = g4[i];
    }
    __syncthreads();

    // histogram both rows (guard padded id = -1)
#pragma unroll
    for (int i = t; i < NSEQ; i += 256) {
        int si = src_ids[(size_t)row * NSEQ + i];
        int di = dst_ids[(size_t)row * NSEQ + i];
        if (si >= 0) atomicAdd(&hist_s[si], 1);
        if (di >= 0) atomicAdd(&hist_d[di], 1);
    }
    __syncthreads();

    // per-position clamped byte offsets for THIS tensor; overflow -> list
#pragma unroll
    for (int i = t; i < NSEQ; i += 256) {
        int id = own_ids[(size_t)row * NSEQ + i];
        int own = 0, cross = 0;
        if (id >= 0) {
            own   = (which == 0) ? hist_s[id] : hist_d[id];
            cross = (which == 0) ? hist_d[id] : hist_s[id];
        }
        if (own >= HOT || cross >= HOT) {
            int k = atomicAdd(&s_novf, 1);
            s_ovf[k] = (unsigned short)i;
        }
        ushort2 off;
        off.x = (unsigned short)(min(own,   HOT - 1) * (NF * 4));
        off.y = (unsigned short)(min(cross, HOT - 1) * (NF * 4));
        s_off[i] = off;
    }
    __syncthreads();

    // ---- hot store stream: vmem pipe carries ONLY stores ----
    float4* __restrict__ o = (float4*)(out + ((size_t)which * BATCH + row) * NSEQ * NF);
    const char* __restrict__ tb = (const char*)s_tbl;
    const int NV = NSEQ * NF / 4;   // 8192 float4
#pragma unroll 4
    for (int e = t; e < NV; e += 256) {
        const int n  = e >> 4;           // position (16 float4 per position)
        const int fb = (e & 15) << 4;    // byte offset within row
        const ushort2 c = s_off[n];
        const float4 a0 = *(const float4*)(tb + (int)c.x + fb);
        const float4 a1 = *(const float4*)(tb + (int)c.y + fb);
        o[e] = make_float4(a0.x + a1.x, a0.y + a1.y, a0.z + a1.z, a0.w + a1.w);
    }

    // ---- rare fixup for counts >= HOT (reads global table) ----
    __syncthreads();
    const int novf = s_novf;
    if (novf > 0) {
        const float4* __restrict__ g4 = (const float4*)g_tbl;
        for (int k = t >> 4; k < novf; k += 16) {
            const int i  = s_ovf[k];
            const int f4 = t & 15;
            const int id = own_ids[(size_t)row * NSEQ + i];
            int own = 0, cross = 0;
            if (id >= 0) {
                own   = (which == 0) ? hist_s[id] : hist_d[id];
                cross = (which == 0) ? hist_d[id] : hist_s[id];
            }
            float4 a0 = g4[own * (NF / 4) + f4];
            float4 a1 = g4[cross * (NF / 4) + f4];
            o[i * 16 + f4] = make_float4(a0.x + a1.x, a0.y + a1.y,
                                         a0.z + a1.z, a0.w + a1.w);
        }
    }
}

extern "C" void kernel_launch(void* const* d_in, const int* in_sizes, int n_in,
                              void* d_out, int out_size, void* d_ws, size_t ws_size,
                              hipStream_t stream) {
    const int*   src_ids = (const int*)d_in[0];
    const int*   dst_ids = (const int*)d_in[1];
    const float* W1 = (const float*)d_in[2];   // [1, F]
    const float* b1 = (const float*)d_in[3];   // [F]
    const float* W2 = (const float*)d_in[4];   // [F, F]
    const float* b2 = (const float*)d_in[5];   // [F]

    float* out = (float*)d_out;   // [2, B, N, F] flat (src encoding, then dst)
    float* tbl = (float*)d_ws;    // TBL_N * NF f32 = 131,328 B

    build_table_kernel<<<TBL_BLOCKS, 256, 0, stream>>>(W1, b1, W2, b2, tbl);
    expand_kernel<<<2 * BATCH, 256, 0, stream>>>(src_ids, dst_ids, tbl, out);
}